// Round 2
// baseline (762.213 us; speedup 1.0000x reference)
//
#include <hip/hip_runtime.h>
#include <math.h>

#define BATCH 2
#define INC   64
#define OUTCH 128
#define NP    8
#define DD    12
#define HH    48
#define WW    48
#define HW    (HH*WW)         // 2304
#define DHW   (DD*HW)         // 27648
#define SPTS  (BATCH*DHW)     // 55296
#define KDIM  (INC*NP)        // 512
#define NELEM (BATCH*OUTCH*DHW) // 7077888
#define NSLAB 8

// workspace layout (floats) — total 123,392 floats = 494 KB (tiny, overrun-safe)
#define WS_W2   0                        // 65536 floats: w2[e][oc]
#define WS_W3   65536                    // float4[13824] = 55296 floats
#define WS_PART (65536 + 55296)          // 2048 floats: psum[128*8], psq[128*8]

// ---------------- prep 0a: w_conv [oc][ic][n] -> w2 [e=n*64+ic][oc] ----------------
__global__ __launch_bounds__(256) void k_transpose_w(const float* __restrict__ wc,
                                                     float* __restrict__ w2) {
    int t = blockIdx.x * 256 + threadIdx.x;   // KDIM*OUTCH = 65536
    int oc = t & 127;
    int e  = t >> 7;
    int ic = e & 63;
    int n  = e >> 6;
    w2[t] = wc[(oc * INC + ic) * NP + n];
}

// ---------------- prep 0b: w_p -> w3 float4[(ic*27+tt)*8+n] = (wz, wx, wy, 0) -------
__global__ __launch_bounds__(256) void k_prep_w3(const float* __restrict__ wp,
                                                 float4* __restrict__ w3) {
    int t = blockIdx.x * 256 + threadIdx.x;   // 13824
    int n   = t & 7;
    int tmp = t >> 3;                         // ic*27+tt
    w3[t] = make_float4(wp[ n       * 1728 + tmp],
                        wp[(8 + n)  * 1728 + tmp],
                        wp[(16 + n) * 1728 + tmp], 0.f);
}

// ---------------- fused: offset-conv + gather + GEMM (pre-BN out) -------------------
// block: 32 spatial points x 128 oc; 256 threads; thread = (point i, sample n)
__global__ __launch_bounds__(256) void k_fused(const float* __restrict__ x,
                                               const float4* __restrict__ w3,
                                               const float* __restrict__ bp,
                                               const float* __restrict__ w2,
                                               float* __restrict__ out) {
    __shared__ float sV[32 * 520];   // [p][e], padded stride 520

    int t  = threadIdx.x;
    int q0 = blockIdx.x * 32;        // DHW%32==0 -> block never straddles batch
    int b  = q0 / DHW;

    int i = t >> 3, n = t & 7;
    int s = q0 + i - b * DHW;
    int d = s / HW; int r = s - d * HW; int h = r / WW; int w = r - h * WW;

    // ---- phase 1: 3x3x3 offset conv for this (point, n): channels n, 8+n, 16+n ----
    int   addr[27];
    float msk[27];
    {
        int u = 0;
        #pragma unroll
        for (int kz = 0; kz < 3; ++kz) {
            int z = d + kz - 1; bool zi = (unsigned)z < DD; int zc = zi ? z : (z < 0 ? 0 : DD - 1);
            #pragma unroll
            for (int kx = 0; kx < 3; ++kx) {
                int xx = h + kx - 1; bool xi = (unsigned)xx < HH; int xc = xi ? xx : (xx < 0 ? 0 : HH - 1);
                #pragma unroll
                for (int ky = 0; ky < 3; ++ky) {
                    int yy = w + ky - 1; bool yi = (unsigned)yy < WW; int yc = yi ? yy : (yy < 0 ? 0 : WW - 1);
                    addr[u] = zc * HW + xc * WW + yc;
                    msk[u]  = (zi && xi && yi) ? 1.f : 0.f;
                    ++u;
                }
            }
        }
    }

    float a0 = bp[n], a1 = bp[8 + n], a2 = bp[16 + n];
    const float* xb = x + b * INC * DHW;
    for (int ic = 0; ic < INC; ++ic) {
        const float* xc = xb + ic * DHW;
        const float4* wq = w3 + (ic * 27) * 8 + n;
        #pragma unroll
        for (int tt = 0; tt < 27; ++tt) {
            float xv = xc[addr[tt]] * msk[tt];
            float4 f = wq[tt * 8];
            a0 = fmaf(xv, f.x, a0);
            a1 = fmaf(xv, f.y, a1);
            a2 = fmaf(xv, f.z, a2);
        }
    }

    // ---- sampling geometry (registers only) ----
    // p_n(8): pnz=[0,0,0,1,1,1,2,2] pnx=[0,0,0,0,0,0,1,1] pny=[0,1,2,0,1,2,0,1]
    float pnz = (n < 6) ? (float)(n / 3) : 2.f;
    float pnx = (n < 6) ? 0.f : 1.f;
    float pny = (n < 6) ? (float)(n % 3) : (float)(n - 6);
    float pz = a0 + (float)d + pnz;
    float px = a1 + (float)h + pnx;
    float py = a2 + (float)w + pny;
    float fz = floorf(pz), fx = floorf(px), fy = floorf(py);
    float z0 = fminf(fmaxf(fz, 0.f), DD - 1.f), z1 = fminf(fmaxf(fz + 1.f, 0.f), DD - 1.f);
    float x0 = fminf(fmaxf(fx, 0.f), HH - 1.f), x1 = fminf(fmaxf(fx + 1.f, 0.f), HH - 1.f);
    float y0 = fminf(fmaxf(fy, 0.f), WW - 1.f), y1 = fminf(fmaxf(fy + 1.f, 0.f), WW - 1.f);
    float pzc = fminf(fmaxf(pz, 0.f), DD - 1.f);
    float pxc = fminf(fmaxf(px, 0.f), HH - 1.f);
    float pyc = fminf(fmaxf(py, 0.f), WW - 1.f);
    float wz0 = 1.f + z0 - pzc, wz1 = 1.f - z1 + pzc;
    float wx0 = 1.f + x0 - pxc, wx1 = 1.f - x1 + pxc;
    float wy0 = 1.f + y0 - pyc, wy1 = 1.f - y1 + pyc;
    float c0 = wz0 * wy0, c1 = wz1 * wy1;
    float g0 = c0 * wx0;   // lt  (z0,x0,y0)
    float g1 = c0 * wx1;   // lb  (z0,x1,y0)
    float g2 = c1 * wx0;   // rt  (z1,x0,y1)
    float g3 = c1 * wx1;   // rb  (z1,x1,y1)
    int iz0 = (int)z0, iz1 = (int)z1, ix0 = (int)x0, ix1 = (int)x1, iy0 = (int)y0, iy1 = (int)y1;
    int i0 = (iz0 * HH + ix0) * WW + iy0;
    int i1 = (iz0 * HH + ix1) * WW + iy0;
    int i2 = (iz1 * HH + ix0) * WW + iy1;
    int i3 = (iz1 * HH + ix1) * WW + iy1;

    // ---- phase 2: gather 64 channels for this (point, n) into V ----
    for (int ic = 0; ic < INC; ++ic) {
        const float* xc = xb + ic * DHW;
        float v = g0 * xc[i0] + g1 * xc[i1] + g2 * xc[i2] + g3 * xc[i3];
        sV[i * 520 + n * 64 + ic] = v;
    }
    __syncthreads();

    // ---- phase 3: out[128 x 32] = W2^T[512x128] dot V[32x512] ----
    {
        int ocg = t & 31, pg = t >> 5;
        int oc0 = ocg * 4, p0 = pg * 4;
        float acc[4][4];
        #pragma unroll
        for (int a = 0; a < 4; ++a)
            #pragma unroll
            for (int c = 0; c < 4; ++c) acc[a][c] = 0.f;

        #pragma unroll 2
        for (int e = 0; e < KDIM; ++e) {
            float4 wv = *reinterpret_cast<const float4*>(&w2[e * OUTCH + oc0]);
            float v0 = sV[(p0 + 0) * 520 + e];
            float v1 = sV[(p0 + 1) * 520 + e];
            float v2 = sV[(p0 + 2) * 520 + e];
            float v3 = sV[(p0 + 3) * 520 + e];
            acc[0][0] = fmaf(wv.x, v0, acc[0][0]);
            acc[0][1] = fmaf(wv.x, v1, acc[0][1]);
            acc[0][2] = fmaf(wv.x, v2, acc[0][2]);
            acc[0][3] = fmaf(wv.x, v3, acc[0][3]);
            acc[1][0] = fmaf(wv.y, v0, acc[1][0]);
            acc[1][1] = fmaf(wv.y, v1, acc[1][1]);
            acc[1][2] = fmaf(wv.y, v2, acc[1][2]);
            acc[1][3] = fmaf(wv.y, v3, acc[1][3]);
            acc[2][0] = fmaf(wv.z, v0, acc[2][0]);
            acc[2][1] = fmaf(wv.z, v1, acc[2][1]);
            acc[2][2] = fmaf(wv.z, v2, acc[2][2]);
            acc[2][3] = fmaf(wv.z, v3, acc[2][3]);
            acc[3][0] = fmaf(wv.w, v0, acc[3][0]);
            acc[3][1] = fmaf(wv.w, v1, acc[3][1]);
            acc[3][2] = fmaf(wv.w, v2, acc[3][2]);
            acc[3][3] = fmaf(wv.w, v3, acc[3][3]);
        }

        int s0 = q0 - b * DHW;
        #pragma unroll
        for (int j = 0; j < 4; ++j) {
            float4 o = make_float4(acc[j][0], acc[j][1], acc[j][2], acc[j][3]);
            *reinterpret_cast<float4*>(&out[(b * OUTCH + oc0 + j) * DHW + s0 + p0]) = o;
        }
    }
}

// ---------------- BN stats: deterministic partial sums (no atomics) ----------------
// grid = 128 channels * 8 slabs; slab j: b = j&1, quarter = j>>1
__global__ __launch_bounds__(256) void k_stats_partial(const float* __restrict__ out,
                                                       float* __restrict__ part) {
    int c = blockIdx.x >> 3;
    int j = blockIdx.x & 7;
    int b = j & 1, quarter = j >> 1;
    const float4* p = reinterpret_cast<const float4*>(
        out + (size_t)(b * OUTCH + c) * DHW + quarter * (DHW / 4));
    float sum = 0.f, ss = 0.f;
    for (int s = threadIdx.x; s < DHW / 16; s += 256) {   // 1728 float4
        float4 v = p[s];
        sum += v.x + v.y + v.z + v.w;
        ss = fmaf(v.x, v.x, ss); ss = fmaf(v.y, v.y, ss);
        ss = fmaf(v.z, v.z, ss); ss = fmaf(v.w, v.w, ss);
    }
    __shared__ float r1[256], r2[256];
    r1[threadIdx.x] = sum; r2[threadIdx.x] = ss;
    __syncthreads();
    for (int ofs = 128; ofs > 0; ofs >>= 1) {
        if (threadIdx.x < ofs) {
            r1[threadIdx.x] += r1[threadIdx.x + ofs];
            r2[threadIdx.x] += r2[threadIdx.x + ofs];
        }
        __syncthreads();
    }
    if (threadIdx.x == 0) {
        part[c * 8 + j]             = r1[0];
        part[OUTCH * 8 + c * 8 + j] = r2[0];
    }
}

// ---------------- BN + SiLU in place (finalize folded in) ----------------
__global__ __launch_bounds__(256) void k_bn_silu(float* __restrict__ out,
                                                 const float* __restrict__ part,
                                                 const float* __restrict__ gamma,
                                                 const float* __restrict__ beta) {
    int t = blockIdx.x * 256 + threadIdx.x;   // NELEM/4 threads
    int base = t * 4;
    int c = (base / DHW) & 127;
    float sum = 0.f, ss = 0.f;
    #pragma unroll
    for (int j = 0; j < 8; ++j) {
        sum += part[c * 8 + j];
        ss  += part[OUTCH * 8 + c * 8 + j];
    }
    const float inv_n = 1.f / (float)(BATCH * DHW);
    float mean = sum * inv_n;
    float var  = ss * inv_n - mean * mean;
    float sc   = gamma[c] * rsqrtf(var + 1e-5f);
    float bi   = beta[c] - mean * sc;
    float4 v = *reinterpret_cast<float4*>(&out[base]);
    float y0 = fmaf(v.x, sc, bi);
    float y1 = fmaf(v.y, sc, bi);
    float y2 = fmaf(v.z, sc, bi);
    float y3 = fmaf(v.w, sc, bi);
    v.x = y0 / (1.f + expf(-y0));
    v.y = y1 / (1.f + expf(-y1));
    v.z = y2 / (1.f + expf(-y2));
    v.w = y3 / (1.f + expf(-y3));
    *reinterpret_cast<float4*>(&out[base]) = v;
}

extern "C" void kernel_launch(void* const* d_in, const int* in_sizes, int n_in,
                              void* d_out, int out_size, void* d_ws, size_t ws_size,
                              hipStream_t stream) {
    const float* x     = (const float*)d_in[0];
    const float* wp    = (const float*)d_in[1];
    const float* bp    = (const float*)d_in[2];
    const float* wc    = (const float*)d_in[3];
    const float* gamma = (const float*)d_in[4];
    const float* beta  = (const float*)d_in[5];
    float* out = (float*)d_out;
    float* ws  = (float*)d_ws;

    float*  w2   = ws + WS_W2;
    float4* w3   = reinterpret_cast<float4*>(ws + WS_W3);
    float*  part = ws + WS_PART;

    k_transpose_w<<<(KDIM * OUTCH) / 256, 256, 0, stream>>>(wc, w2);
    k_prep_w3<<<13824 / 256, 256, 0, stream>>>(wp, w3);
    k_fused<<<SPTS / 32, 256, 0, stream>>>(x, w3, bp, w2, out);
    k_stats_partial<<<OUTCH * NSLAB, 256, 0, stream>>>(out, part);
    k_bn_silu<<<(NELEM / 4) / 256, 256, 0, stream>>>(out, part, gamma, beta);
}

// Round 3
// 610.624 us; speedup vs baseline: 1.2483x; 1.2483x over previous
//
#include <hip/hip_runtime.h>
#include <math.h>

#define BATCH 2
#define INC   64
#define OUTCH 128
#define NP    8
#define DD    12
#define HH    48
#define WW    48
#define HW    (HH*WW)         // 2304
#define DHW   (DD*HW)         // 27648
#define SPTS  (BATCH*DHW)     // 55296
#define KDIM  (INC*NP)        // 512
#define NELEM (BATCH*OUTCH*DHW) // 7077888
#define VSTRIDE 520           // bf16 elems per p-row in LDS (512 + 8 pad, 16B-aligned rows)

// workspace layout (floats) — ~360 KB total
#define WS_W2B  0                         // ushort[65536] = 32768 floats: A-fragment-packed bf16 weights
#define WS_W3   32768                     // float4[13824] = 55296 floats
#define WS_PART (32768 + 55296)           // 2048 floats: psum/psq partials

typedef __attribute__((ext_vector_type(8))) short short8;
typedef __attribute__((ext_vector_type(4))) float floatx4;

__device__ __forceinline__ ushort f2bf(float f) {
    unsigned u = __float_as_uint(f);
    unsigned r = (u + 0x7fffu + ((u >> 16) & 1u)) >> 16;
    return (ushort)r;
}

// ---- prep 0a: wc [oc][ic][n] -> w2b bf16, A-fragment layout: w2b[(kq*128+oc)*8+j], e=kq*8+j, e=n*64+ic
__global__ __launch_bounds__(256) void k_prep_w2b(const float* __restrict__ wc,
                                                  ushort* __restrict__ w2b) {
    int t = blockIdx.x * 256 + threadIdx.x;   // 65536
    int j  = t & 7;
    int oc = (t >> 3) & 127;
    int kq = t >> 10;
    int e  = kq * 8 + j;
    int ic = e & 63;
    int n  = e >> 6;
    w2b[t] = f2bf(wc[(oc * INC + ic) * NP + n]);
}

// ---- prep 0b: w_p -> w3 float4[(ic*27+tt)*8+n] = (wz, wx, wy, 0) ----
__global__ __launch_bounds__(256) void k_prep_w3(const float* __restrict__ wp,
                                                 float4* __restrict__ w3) {
    int t = blockIdx.x * 256 + threadIdx.x;   // 13824
    int n   = t & 7;
    int tmp = t >> 3;                         // ic*27+tt
    w3[t] = make_float4(wp[ n       * 1728 + tmp],
                        wp[(8 + n)  * 1728 + tmp],
                        wp[(16 + n) * 1728 + tmp], 0.f);
}

// ---- fused: offset-conv + gather (fp32) + MFMA bf16 GEMM ----
// block: 32 spatial points x 128 oc; 256 threads; conv/gather thread = (point i, sample n)
__global__ __launch_bounds__(256, 4) void k_fused(const float* __restrict__ x,
                                                  const float4* __restrict__ w3,
                                                  const float* __restrict__ bp,
                                                  const ushort* __restrict__ w2b,
                                                  float* __restrict__ out) {
    __shared__ __align__(16) ushort sVb[32 * VSTRIDE];   // V[p][e] bf16, 33,280 B

    int t  = threadIdx.x;
    int q0 = blockIdx.x * 32;        // DHW%32==0 -> block never straddles batch
    int bb = q0 / DHW;

    int i = t >> 3, n = t & 7;
    int s = q0 + i - bb * DHW;
    int d = s / HW; int r = s - d * HW; int h = r / WW; int w = r - h * WW;

    const float* xb = x + bb * INC * DHW;

    // ---- phase 1: 3x3x3 offset conv, kz-sliced to keep VGPRs low ----
    float a0 = bp[n], a1 = bp[8 + n], a2 = bp[16 + n];
    #pragma unroll 1
    for (int kz = 0; kz < 3; ++kz) {
        int z = d + kz - 1; bool zi = (unsigned)z < DD; int zc = zi ? z : (z < 0 ? 0 : DD - 1);
        int   addr9[9];
        float msk9[9];
        {
            int u = 0;
            #pragma unroll
            for (int kx = 0; kx < 3; ++kx) {
                int xx = h + kx - 1; bool xi = (unsigned)xx < HH; int xc2 = xi ? xx : (xx < 0 ? 0 : HH - 1);
                #pragma unroll
                for (int ky = 0; ky < 3; ++ky) {
                    int yy = w + ky - 1; bool yi = (unsigned)yy < WW; int yc = yi ? yy : (yy < 0 ? 0 : WW - 1);
                    addr9[u] = zc * HW + xc2 * WW + yc;
                    msk9[u]  = (zi && xi && yi) ? 1.f : 0.f;
                    ++u;
                }
            }
        }
        for (int ic = 0; ic < INC; ++ic) {
            const float*  xc = xb + ic * DHW;
            const float4* wq = w3 + (ic * 27 + kz * 9) * 8 + n;
            #pragma unroll
            for (int u = 0; u < 9; ++u) {
                float xv = xc[addr9[u]] * msk9[u];
                float4 f = wq[u * 8];
                a0 = fmaf(xv, f.x, a0);
                a1 = fmaf(xv, f.y, a1);
                a2 = fmaf(xv, f.z, a2);
            }
        }
    }

    // ---- sampling geometry (registers only) ----
    float pnz = (n < 6) ? (float)(n / 3) : 2.f;
    float pnx = (n < 6) ? 0.f : 1.f;
    float pny = (n < 6) ? (float)(n % 3) : (float)(n - 6);
    float pz = a0 + (float)d + pnz;
    float px = a1 + (float)h + pnx;
    float py = a2 + (float)w + pny;
    float fz = floorf(pz), fx = floorf(px), fy = floorf(py);
    float z0 = fminf(fmaxf(fz, 0.f), DD - 1.f), z1 = fminf(fmaxf(fz + 1.f, 0.f), DD - 1.f);
    float x0 = fminf(fmaxf(fx, 0.f), HH - 1.f), x1 = fminf(fmaxf(fx + 1.f, 0.f), HH - 1.f);
    float y0 = fminf(fmaxf(fy, 0.f), WW - 1.f), y1 = fminf(fmaxf(fy + 1.f, 0.f), WW - 1.f);
    float pzc = fminf(fmaxf(pz, 0.f), DD - 1.f);
    float pxc = fminf(fmaxf(px, 0.f), HH - 1.f);
    float pyc = fminf(fmaxf(py, 0.f), WW - 1.f);
    float wz0 = 1.f + z0 - pzc, wz1 = 1.f - z1 + pzc;
    float wx0 = 1.f + x0 - pxc, wx1 = 1.f - x1 + pxc;
    float wy0 = 1.f + y0 - pyc, wy1 = 1.f - y1 + pyc;
    float c0 = wz0 * wy0, c1 = wz1 * wy1;
    float g0 = c0 * wx0;   // (z0,x0,y0)
    float g1 = c0 * wx1;   // (z0,x1,y0)
    float g2 = c1 * wx0;   // (z1,x0,y1)
    float g3 = c1 * wx1;   // (z1,x1,y1)
    int iz0 = (int)z0, iz1 = (int)z1, ix0 = (int)x0, ix1 = (int)x1, iy0 = (int)y0, iy1 = (int)y1;
    int i0 = (iz0 * HH + ix0) * WW + iy0;
    int i1 = (iz0 * HH + ix1) * WW + iy0;
    int i2 = (iz1 * HH + ix0) * WW + iy1;
    int i3 = (iz1 * HH + ix1) * WW + iy1;

    // ---- phase 2: gather 64 channels (2 ic per iter), pack bf16x2, write LDS ----
    {
        unsigned* sVbU = reinterpret_cast<unsigned*>(sVb);
        int wbase = i * (VSTRIDE / 2) + n * 32;
        for (int icp = 0; icp < 32; ++icp) {
            const float* xc  = xb + (2 * icp) * DHW;
            const float* xc2 = xc + DHW;
            float vl = g0 * xc[i0]  + g1 * xc[i1]  + g2 * xc[i2]  + g3 * xc[i3];
            float vh = g0 * xc2[i0] + g1 * xc2[i1] + g2 * xc2[i2] + g3 * xc2[i3];
            sVbU[wbase + icp] = (unsigned)f2bf(vl) | ((unsigned)f2bf(vh) << 16);
        }
    }
    __syncthreads();

    // ---- phase 3: out[128oc x 32p] via mfma_f32_16x16x32_bf16 ----
    // wave wid owns oc-blocks {2wid, 2wid+1} x p-blocks {0,1} (4 16x16 tiles)
    {
        int lane = t & 63;
        int wid  = t >> 6;
        int l16  = lane & 15;
        int q    = lane >> 4;            // 0..3: k-chunk selector
        int ocA0 = (wid * 2) * 16 + l16; // A rows for tile pair
        const ushort* A0 = w2b + ((q * 128) + ocA0) * 8;     // +kt*4096 per kt
        const ushort* A1 = A0 + 16 * 8;
        const ushort* B0 = sVb + l16 * VSTRIDE + q * 8;      // +kt*32 per kt
        const ushort* B1 = B0 + 16 * VSTRIDE;

        floatx4 c00 = {0.f, 0.f, 0.f, 0.f};
        floatx4 c01 = {0.f, 0.f, 0.f, 0.f};
        floatx4 c10 = {0.f, 0.f, 0.f, 0.f};
        floatx4 c11 = {0.f, 0.f, 0.f, 0.f};

        #pragma unroll 4
        for (int kt = 0; kt < 16; ++kt) {
            short8 af0 = *reinterpret_cast<const short8*>(A0 + kt * 4096);
            short8 af1 = *reinterpret_cast<const short8*>(A1 + kt * 4096);
            short8 bf0 = *reinterpret_cast<const short8*>(B0 + kt * 32);
            short8 bf1 = *reinterpret_cast<const short8*>(B1 + kt * 32);
            c00 = __builtin_amdgcn_mfma_f32_16x16x32_bf16(af0, bf0, c00, 0, 0, 0);
            c01 = __builtin_amdgcn_mfma_f32_16x16x32_bf16(af0, bf1, c01, 0, 0, 0);
            c10 = __builtin_amdgcn_mfma_f32_16x16x32_bf16(af1, bf0, c10, 0, 0, 0);
            c11 = __builtin_amdgcn_mfma_f32_16x16x32_bf16(af1, bf1, c11, 0, 0, 0);
        }

        int s0 = q0 - bb * DHW;
        float* outb = out + (size_t)bb * OUTCH * DHW + s0;
        int ocRow = (wid * 2) * 16 + q * 4;   // D row = (lane>>4)*4 + reg
        #pragma unroll
        for (int rg = 0; rg < 4; ++rg) {
            outb[(ocRow + rg) * DHW + l16]            = c00[rg];
            outb[(ocRow + rg) * DHW + 16 + l16]       = c01[rg];
            outb[(ocRow + 16 + rg) * DHW + l16]       = c10[rg];
            outb[(ocRow + 16 + rg) * DHW + 16 + l16]  = c11[rg];
        }
    }
}

// ---- BN stats: deterministic partial sums (no atomics) ----
__global__ __launch_bounds__(256) void k_stats_partial(const float* __restrict__ out,
                                                       float* __restrict__ part) {
    int c = blockIdx.x >> 3;
    int j = blockIdx.x & 7;
    int b = j & 1, quarter = j >> 1;
    const float4* p = reinterpret_cast<const float4*>(
        out + (size_t)(b * OUTCH + c) * DHW + quarter * (DHW / 4));
    float sum = 0.f, ss = 0.f;
    for (int s = threadIdx.x; s < DHW / 16; s += 256) {
        float4 v = p[s];
        sum += v.x + v.y + v.z + v.w;
        ss = fmaf(v.x, v.x, ss); ss = fmaf(v.y, v.y, ss);
        ss = fmaf(v.z, v.z, ss); ss = fmaf(v.w, v.w, ss);
    }
    __shared__ float r1[256], r2[256];
    r1[threadIdx.x] = sum; r2[threadIdx.x] = ss;
    __syncthreads();
    for (int ofs = 128; ofs > 0; ofs >>= 1) {
        if (threadIdx.x < ofs) {
            r1[threadIdx.x] += r1[threadIdx.x + ofs];
            r2[threadIdx.x] += r2[threadIdx.x + ofs];
        }
        __syncthreads();
    }
    if (threadIdx.x == 0) {
        part[c * 8 + j]             = r1[0];
        part[OUTCH * 8 + c * 8 + j] = r2[0];
    }
}

// ---- BN + SiLU in place ----
__global__ __launch_bounds__(256) void k_bn_silu(float* __restrict__ out,
                                                 const float* __restrict__ part,
                                                 const float* __restrict__ gamma,
                                                 const float* __restrict__ beta) {
    int t = blockIdx.x * 256 + threadIdx.x;
    int base = t * 4;
    int c = (base / DHW) & 127;
    float sum = 0.f, ss = 0.f;
    #pragma unroll
    for (int j = 0; j < 8; ++j) {
        sum += part[c * 8 + j];
        ss  += part[OUTCH * 8 + c * 8 + j];
    }
    const float inv_n = 1.f / (float)(BATCH * DHW);
    float mean = sum * inv_n;
    float var  = ss * inv_n - mean * mean;
    float sc   = gamma[c] * rsqrtf(var + 1e-5f);
    float bi   = beta[c] - mean * sc;
    float4 v = *reinterpret_cast<float4*>(&out[base]);
    float y0 = fmaf(v.x, sc, bi);
    float y1 = fmaf(v.y, sc, bi);
    float y2 = fmaf(v.z, sc, bi);
    float y3 = fmaf(v.w, sc, bi);
    v.x = y0 / (1.f + expf(-y0));
    v.y = y1 / (1.f + expf(-y1));
    v.z = y2 / (1.f + expf(-y2));
    v.w = y3 / (1.f + expf(-y3));
    *reinterpret_cast<float4*>(&out[base]) = v;
}

extern "C" void kernel_launch(void* const* d_in, const int* in_sizes, int n_in,
                              void* d_out, int out_size, void* d_ws, size_t ws_size,
                              hipStream_t stream) {
    const float* x     = (const float*)d_in[0];
    const float* wp    = (const float*)d_in[1];
    const float* bp    = (const float*)d_in[2];
    const float* wc    = (const float*)d_in[3];
    const float* gamma = (const float*)d_in[4];
    const float* beta  = (const float*)d_in[5];
    float* out = (float*)d_out;
    float* ws  = (float*)d_ws;

    ushort* w2b = reinterpret_cast<ushort*>(ws + WS_W2B);
    float4* w3  = reinterpret_cast<float4*>(ws + WS_W3);
    float*  part = ws + WS_PART;

    k_prep_w2b<<<65536 / 256, 256, 0, stream>>>(wc, w2b);
    k_prep_w3<<<13824 / 256, 256, 0, stream>>>(wp, w3);
    k_fused<<<SPTS / 32, 256, 0, stream>>>(x, w3, bp, w2b, out);
    k_stats_partial<<<OUTCH * 8, 256, 0, stream>>>(out, part);
    k_bn_silu<<<(NELEM / 4) / 256, 256, 0, stream>>>(out, part, gamma, beta);
}

// Round 5
// 548.907 us; speedup vs baseline: 1.3886x; 1.1124x over previous
//
#include <hip/hip_runtime.h>
#include <math.h>

#define BATCH 2
#define INC   64
#define OUTCH 128
#define NP    8
#define DD    12
#define HH    48
#define WW    48
#define HW    (HH*WW)         // 2304
#define DHW   (DD*HW)         // 27648
#define SPTS  (BATCH*DHW)     // 55296
#define KDIM  (INC*NP)        // 512
#define NELEM (BATCH*OUTCH*DHW) // 7077888
#define VSTRIDE 520           // bf16 elems per p-row in LDS for GEMM2 B

// workspace layout (floats) — total 1,859,584 floats = 7.44 MB
#define WS_W2B  0                          // ushort[65536]: GEMM2 A bf16 fragments
#define WS_W3   32768                      // float4[13824]: conv weight triples
#define WS_PART 88064                      // 2048 floats: psum/psq partials
#define WS_XT   90112                      // uint[1769472]: x as [b][s][ic/2] bf16x2

typedef __attribute__((ext_vector_type(8))) short short8;
typedef __attribute__((ext_vector_type(4))) float floatx4;

__device__ __forceinline__ ushort f2bf(float f) {
    unsigned u = __float_as_uint(f);
    unsigned r = (u + 0x7fffu + ((u >> 16) & 1u)) >> 16;
    return (ushort)r;
}

__device__ __forceinline__ unsigned interp2(unsigned a, unsigned b, unsigned c, unsigned d,
                                            float g0, float g1, float g2, float g3) {
    float vl = g0 * __uint_as_float(a << 16) + g1 * __uint_as_float(b << 16)
             + g2 * __uint_as_float(c << 16) + g3 * __uint_as_float(d << 16);
    float vh = g0 * __uint_as_float(a & 0xffff0000u) + g1 * __uint_as_float(b & 0xffff0000u)
             + g2 * __uint_as_float(c & 0xffff0000u) + g3 * __uint_as_float(d & 0xffff0000u);
    return (unsigned)f2bf(vl) | ((unsigned)f2bf(vh) << 16);
}

// ---- prep 0a: wc [oc][ic][n] -> w2b bf16 fragment layout [(kq*128+oc)*8+j], e=kq*8+j=n*64+ic
__global__ __launch_bounds__(256) void k_prep_w2b(const float* __restrict__ wc,
                                                  ushort* __restrict__ w2b) {
    int t = blockIdx.x * 256 + threadIdx.x;   // 65536
    int j  = t & 7;
    int oc = (t >> 3) & 127;
    int kq = t >> 10;
    int e  = kq * 8 + j;
    int ic = e & 63;
    int n  = e >> 6;
    w2b[t] = f2bf(wc[(oc * INC + ic) * NP + n]);
}

// ---- prep 0b: w_p -> w3 float4[(ic*27+tt)*8+n] = (wz, wx, wy, 0)  [fp32 — precision critical]
__global__ __launch_bounds__(256) void k_prep_w3(const float* __restrict__ wp,
                                                 float4* __restrict__ w3) {
    int t = blockIdx.x * 256 + threadIdx.x;   // 13824
    int n   = t & 7;
    int tmp = t >> 3;                         // ic*27+tt
    w3[t] = make_float4(wp[ n       * 1728 + tmp],
                        wp[(8 + n)  * 1728 + tmp],
                        wp[(16 + n) * 1728 + tmp], 0.f);
}

// ---- prep 0c: x NCDHW fp32 -> xT [b][s][ic] bf16 (packed pairs) ----
__global__ __launch_bounds__(256) void k_transpose_x(const float* __restrict__ x,
                                                     unsigned* __restrict__ xTu) {
    int t = blockIdx.x * 256 + threadIdx.x;   // SPTS*32 = 1769472
    int icp = t & 31;
    int sg  = t >> 5;                         // b*DHW + s
    int b   = sg / DHW;
    int s   = sg - b * DHW;
    const float* xb = x + (size_t)b * INC * DHW + s;
    float v0 = xb[(2 * icp) * DHW];
    float v1 = xb[(2 * icp + 1) * DHW];
    xTu[t] = (unsigned)f2bf(v0) | ((unsigned)f2bf(v1) << 16);
}

// ---- fused: fp32 offset-conv + bf16 vector gather + MFMA GEMM2 ----
// block: 32 spatial points x 128 oc; 256 threads; conv/gather thread = (point i, sample n)
__global__ __launch_bounds__(256, 4) void k_fused(const float* __restrict__ x,
                                                  const unsigned* __restrict__ xTu,
                                                  const float4* __restrict__ w3,
                                                  const float* __restrict__ bp,
                                                  const ushort* __restrict__ w2b,
                                                  float* __restrict__ out) {
    __shared__ __align__(16) ushort sVb[32 * VSTRIDE];   // V[p][e] bf16, 33,280 B

    int t  = threadIdx.x;
    int q0 = blockIdx.x * 32;        // DHW%32==0 -> block never straddles batch
    int bb = q0 / DHW;

    int i = t >> 3, n = t & 7;
    int s = q0 + i - bb * DHW;
    int d = s / HW; int r = s - d * HW; int h = r / WW; int w = r - h * WW;

    const float* xb = x + (size_t)bb * INC * DHW;

    // ---- phase 1: 3x3x3 offset conv in fp32 (precision-critical: offsets feed floor()) ----
    float a0 = bp[n], a1 = bp[8 + n], a2 = bp[16 + n];
    #pragma unroll 1
    for (int kz = 0; kz < 3; ++kz) {
        int z = d + kz - 1; bool zi = (unsigned)z < DD; int zc = zi ? z : (z < 0 ? 0 : DD - 1);
        int   addr9[9];
        float msk9[9];
        {
            int u = 0;
            #pragma unroll
            for (int kx = 0; kx < 3; ++kx) {
                int xx = h + kx - 1; bool xi = (unsigned)xx < HH; int xc2 = xi ? xx : (xx < 0 ? 0 : HH - 1);
                #pragma unroll
                for (int ky = 0; ky < 3; ++ky) {
                    int yy = w + ky - 1; bool yi = (unsigned)yy < WW; int yc = yi ? yy : (yy < 0 ? 0 : WW - 1);
                    addr9[u] = zc * HW + xc2 * WW + yc;
                    msk9[u]  = (zi && xi && yi) ? 1.f : 0.f;
                    ++u;
                }
            }
        }
        for (int ic = 0; ic < INC; ++ic) {
            const float*  xc = xb + ic * DHW;
            const float4* wq = w3 + (ic * 27 + kz * 9) * 8 + n;
            #pragma unroll
            for (int u = 0; u < 9; ++u) {
                float xv = xc[addr9[u]] * msk9[u];
                float4 f = wq[u * 8];
                a0 = fmaf(xv, f.x, a0);
                a1 = fmaf(xv, f.y, a1);
                a2 = fmaf(xv, f.z, a2);
            }
        }
    }

    // ---- sampling geometry (fp32, registers only) ----
    float pnz = (n < 6) ? (float)(n / 3) : 2.f;
    float pnx = (n < 6) ? 0.f : 1.f;
    float pny = (n < 6) ? (float)(n % 3) : (float)(n - 6);
    float pz = a0 + (float)d + pnz;
    float px = a1 + (float)h + pnx;
    float py = a2 + (float)w + pny;
    float fz = floorf(pz), fx = floorf(px), fy = floorf(py);
    float z0 = fminf(fmaxf(fz, 0.f), DD - 1.f), z1 = fminf(fmaxf(fz + 1.f, 0.f), DD - 1.f);
    float x0 = fminf(fmaxf(fx, 0.f), HH - 1.f), x1 = fminf(fmaxf(fx + 1.f, 0.f), HH - 1.f);
    float y0 = fminf(fmaxf(fy, 0.f), WW - 1.f), y1 = fminf(fmaxf(fy + 1.f, 0.f), WW - 1.f);
    float pzc = fminf(fmaxf(pz, 0.f), DD - 1.f);
    float pxc = fminf(fmaxf(px, 0.f), HH - 1.f);
    float pyc = fminf(fmaxf(py, 0.f), WW - 1.f);
    float wz0 = 1.f + z0 - pzc, wz1 = 1.f - z1 + pzc;
    float wx0 = 1.f + x0 - pxc, wx1 = 1.f - x1 + pxc;
    float wy0 = 1.f + y0 - pyc, wy1 = 1.f - y1 + pyc;
    float c0 = wz0 * wy0, c1 = wz1 * wy1;
    float g0 = c0 * wx0;   // (z0,x0,y0)
    float g1 = c0 * wx1;   // (z0,x1,y0)
    float g2 = c1 * wx0;   // (z1,x0,y1)
    float g3 = c1 * wx1;   // (z1,x1,y1)
    int iz0 = (int)z0, iz1 = (int)z1, ix0 = (int)x0, ix1 = (int)x1, iy0 = (int)y0, iy1 = (int)y1;
    int i0 = (iz0 * HH + ix0) * WW + iy0;
    int i1 = (iz0 * HH + ix1) * WW + iy0;
    int i2 = (iz1 * HH + ix0) * WW + iy1;
    int i3 = (iz1 * HH + ix1) * WW + iy1;

    // ---- phase 2: vector gather from bf16 NDHWC xT (4 corners x 64 ch contiguous) ----
    {
        const unsigned* xTb = xTu + (size_t)bb * DHW * 32;
        const uint4* p0 = reinterpret_cast<const uint4*>(xTb + (size_t)i0 * 32);
        const uint4* p1 = reinterpret_cast<const uint4*>(xTb + (size_t)i1 * 32);
        const uint4* p2 = reinterpret_cast<const uint4*>(xTb + (size_t)i2 * 32);
        const uint4* p3 = reinterpret_cast<const uint4*>(xTb + (size_t)i3 * 32);
        unsigned* sVbU = reinterpret_cast<unsigned*>(sVb);
        int wbase = i * (VSTRIDE / 2) + n * 32;
        #pragma unroll
        for (int e = 0; e < 8; ++e) {
            uint4 A = p0[e], B = p1[e], C = p2[e], D2 = p3[e];
            sVbU[wbase + e * 4 + 0] = interp2(A.x, B.x, C.x, D2.x, g0, g1, g2, g3);
            sVbU[wbase + e * 4 + 1] = interp2(A.y, B.y, C.y, D2.y, g0, g1, g2, g3);
            sVbU[wbase + e * 4 + 2] = interp2(A.z, B.z, C.z, D2.z, g0, g1, g2, g3);
            sVbU[wbase + e * 4 + 3] = interp2(A.w, B.w, C.w, D2.w, g0, g1, g2, g3);
        }
    }
    __syncthreads();

    // ---- phase 3: out[128oc x 32p] via mfma_f32_16x16x32_bf16 ----
    {
        int lane = t & 63;
        int wid  = t >> 6;
        int l16  = lane & 15;
        int q    = lane >> 4;
        int ocA0 = (wid * 2) * 16 + l16;
        const ushort* A0 = w2b + ((q * 128) + ocA0) * 8;     // +kt*4096
        const ushort* A1 = A0 + 16 * 8;
        const ushort* B0 = sVb + l16 * VSTRIDE + q * 8;      // +kt*32
        const ushort* B1 = B0 + 16 * VSTRIDE;

        floatx4 c00 = {0.f, 0.f, 0.f, 0.f};
        floatx4 c01 = {0.f, 0.f, 0.f, 0.f};
        floatx4 c10 = {0.f, 0.f, 0.f, 0.f};
        floatx4 c11 = {0.f, 0.f, 0.f, 0.f};

        #pragma unroll 4
        for (int kt = 0; kt < 16; ++kt) {
            short8 af0 = *reinterpret_cast<const short8*>(A0 + kt * 4096);
            short8 af1 = *reinterpret_cast<const short8*>(A1 + kt * 4096);
            short8 bf0 = *reinterpret_cast<const short8*>(B0 + kt * 32);
            short8 bf1 = *reinterpret_cast<const short8*>(B1 + kt * 32);
            c00 = __builtin_amdgcn_mfma_f32_16x16x32_bf16(af0, bf0, c00, 0, 0, 0);
            c01 = __builtin_amdgcn_mfma_f32_16x16x32_bf16(af0, bf1, c01, 0, 0, 0);
            c10 = __builtin_amdgcn_mfma_f32_16x16x32_bf16(af1, bf0, c10, 0, 0, 0);
            c11 = __builtin_amdgcn_mfma_f32_16x16x32_bf16(af1, bf1, c11, 0, 0, 0);
        }

        int s0 = q0 - bb * DHW;
        float* outb = out + (size_t)bb * OUTCH * DHW + s0;
        int ocRow = (wid * 2) * 16 + q * 4;
        #pragma unroll
        for (int rg = 0; rg < 4; ++rg) {
            outb[(ocRow + rg) * DHW + l16]            = c00[rg];
            outb[(ocRow + rg) * DHW + 16 + l16]       = c01[rg];
            outb[(ocRow + 16 + rg) * DHW + l16]       = c10[rg];
            outb[(ocRow + 16 + rg) * DHW + 16 + l16]  = c11[rg];
        }
    }
}

// ---- BN stats: deterministic partial sums ----
__global__ __launch_bounds__(256) void k_stats_partial(const float* __restrict__ out,
                                                       float* __restrict__ part) {
    int c = blockIdx.x >> 3;
    int j = blockIdx.x & 7;
    int b = j & 1, quarter = j >> 1;
    const float4* p = reinterpret_cast<const float4*>(
        out + (size_t)(b * OUTCH + c) * DHW + quarter * (DHW / 4));
    float sum = 0.f, ss = 0.f;
    for (int s = threadIdx.x; s < DHW / 16; s += 256) {
        float4 v = p[s];
        sum += v.x + v.y + v.z + v.w;
        ss = fmaf(v.x, v.x, ss); ss = fmaf(v.y, v.y, ss);
        ss = fmaf(v.z, v.z, ss); ss = fmaf(v.w, v.w, ss);
    }
    __shared__ float r1[256], r2[256];
    r1[threadIdx.x] = sum; r2[threadIdx.x] = ss;
    __syncthreads();
    for (int ofs = 128; ofs > 0; ofs >>= 1) {
        if (threadIdx.x < ofs) {
            r1[threadIdx.x] += r1[threadIdx.x + ofs];
            r2[threadIdx.x] += r2[threadIdx.x + ofs];
        }
        __syncthreads();
    }
    if (threadIdx.x == 0) {
        part[c * 8 + j]             = r1[0];
        part[OUTCH * 8 + c * 8 + j] = r2[0];
    }
}

// ---- BN + SiLU in place ----
__global__ __launch_bounds__(256) void k_bn_silu(float* __restrict__ out,
                                                 const float* __restrict__ part,
                                                 const float* __restrict__ gamma,
                                                 const float* __restrict__ beta) {
    int t = blockIdx.x * 256 + threadIdx.x;
    int base = t * 4;
    int c = (base / DHW) & 127;
    float sum = 0.f, ss = 0.f;
    #pragma unroll
    for (int j = 0; j < 8; ++j) {
        sum += part[c * 8 + j];
        ss  += part[OUTCH * 8 + c * 8 + j];
    }
    const float inv_n = 1.f / (float)(BATCH * DHW);
    float mean = sum * inv_n;
    float var  = ss * inv_n - mean * mean;
    float sc   = gamma[c] * rsqrtf(var + 1e-5f);
    float bi   = beta[c] - mean * sc;
    float4 v = *reinterpret_cast<float4*>(&out[base]);
    float y0 = fmaf(v.x, sc, bi);
    float y1 = fmaf(v.y, sc, bi);
    float y2 = fmaf(v.z, sc, bi);
    float y3 = fmaf(v.w, sc, bi);
    v.x = y0 / (1.f + expf(-y0));
    v.y = y1 / (1.f + expf(-y1));
    v.z = y2 / (1.f + expf(-y2));
    v.w = y3 / (1.f + expf(-y3));
    *reinterpret_cast<float4*>(&out[base]) = v;
}

extern "C" void kernel_launch(void* const* d_in, const int* in_sizes, int n_in,
                              void* d_out, int out_size, void* d_ws, size_t ws_size,
                              hipStream_t stream) {
    const float* x     = (const float*)d_in[0];
    const float* wp    = (const float*)d_in[1];
    const float* bp    = (const float*)d_in[2];
    const float* wc    = (const float*)d_in[3];
    const float* gamma = (const float*)d_in[4];
    const float* beta  = (const float*)d_in[5];
    float* out = (float*)d_out;
    float* ws  = (float*)d_ws;

    ushort*   w2b  = reinterpret_cast<ushort*>(ws + WS_W2B);
    float4*   w3   = reinterpret_cast<float4*>(ws + WS_W3);
    float*    part = ws + WS_PART;
    unsigned* xTu  = reinterpret_cast<unsigned*>(ws + WS_XT);

    k_prep_w2b<<<65536 / 256, 256, 0, stream>>>(wc, w2b);
    k_prep_w3<<<13824 / 256, 256, 0, stream>>>(wp, w3);
    k_transpose_x<<<(SPTS * 32) / 256, 256, 0, stream>>>(x, xTu);
    k_fused<<<SPTS / 32, 256, 0, stream>>>(x, xTu, w3, bp, w2b, out);
    k_stats_partial<<<OUTCH * 8, 256, 0, stream>>>(out, part);
    k_bn_silu<<<(NELEM / 4) / 256, 256, 0, stream>>>(out, part, gamma, beta);
}